// Round 14
// baseline (441.321 us; speedup 1.0000x reference)
//
#include <hip/hip_runtime.h>
#include <math.h>

#define BB 4
#define SS 2048
#define DD 768
#define HH 8
#define DHD 96
#define SEP_ID 102
#define CHUNK 352
#define NCH_MAX 3
#define QT64 11
#define SLOTB 12800  // 64q*96d bf16 (12288) + m[64],l[64] f32 (512)

typedef __attribute__((ext_vector_type(8))) short bf16x8;
typedef __attribute__((ext_vector_type(4))) float f32x4;

static __device__ __forceinline__ float gelu_tanh(float x) {
  float x3 = x * x * x;
  float t = tanhf(0.7978845608028654f * (x + 0.044715f * x3));
  return 0.5f * x * (1.0f + t);
}

static __device__ __forceinline__ unsigned short f2bf(float f) {
  unsigned int u = __float_as_uint(f);
  u = (u + 0x7FFF + ((u >> 16) & 1)) >> 16;
  return (unsigned short)u;
}

static __device__ __forceinline__ float bf2f(unsigned short u) {
  return __uint_as_float(((unsigned int)u) << 16);
}

#define MFMA16(A, B, C) __builtin_amdgcn_mfma_f32_16x16x32_bf16(A, B, C, 0, 0, 0)

// async global -> LDS, 16B per lane
static __device__ __forceinline__ void gl16(const void* g, void* l) {
  __builtin_amdgcn_global_load_lds(
      (__attribute__((address_space(1))) unsigned int*)g,
      (__attribute__((address_space(3))) unsigned int*)l, 16, 0, 0);
}

static __device__ __forceinline__ float wave_sum(float v) {
#pragma unroll
  for (int off = 32; off > 0; off >>= 1) v += __shfl_xor(v, off);
  return v;
}

// ---------------- fused prep: seg+counters (4) + conv/copy (1536) + wtrans (864) ---------
__global__ __launch_bounds__(256) void prep(
    const int* __restrict__ ids, int* __restrict__ seg, int* __restrict__ cnt,
    const float* __restrict__ x, unsigned short* __restrict__ xbf,
    float* __restrict__ out, int n4,
    const float* __restrict__ W0, const float* __restrict__ W1,
    const float* __restrict__ W2, const float* __restrict__ W3,
    const float* __restrict__ W4, const float* __restrict__ W5,
    unsigned short* __restrict__ Wt) {
  __shared__ char smem[64 * 65 * 4];
  int bx = blockIdx.x;
  if (bx < 4) {
    if (bx == 0)
      for (int i = threadIdx.x; i < 496; i += 256) cnt[i] = 0;
    int* s1 = (int*)smem;
    int* s2 = s1 + 256;
    int b = bx;
    const int* row = ids + (size_t)b * SS;
    int m1 = SS, m2 = SS;
    for (int i = threadIdx.x; i < SS; i += 256) {
      if (row[i] == SEP_ID) {
        if (i < m1) { m2 = m1; m1 = i; }
        else if (i < m2) { m2 = i; }
      }
    }
    s1[threadIdx.x] = m1; s2[threadIdx.x] = m2;
    __syncthreads();
    for (int off = 128; off > 0; off >>= 1) {
      if (threadIdx.x < off) {
        int a1 = s1[threadIdx.x], a2 = s2[threadIdx.x];
        int b1 = s1[threadIdx.x + off], b2 = s2[threadIdx.x + off];
        s1[threadIdx.x] = min(a1, b1);
        s2[threadIdx.x] = min(max(a1, b1), min(a2, b2));
      }
      __syncthreads();
    }
    if (threadIdx.x == 0) {
      int first = s1[0], second = s2[0];
      bool has2 = (second < SS);
      int mid = SS / 2;
      int src_end = has2 ? first : mid;
      int hyp_lo = has2 ? (first + 1) : mid;
      int hyp_hi = has2 ? second : (SS - 1);
      int valid = ((src_end - 1) > 0 && (hyp_hi - hyp_lo) > 0) ? 1 : 0;
      if (!valid) { src_end = 1; hyp_lo = 0; hyp_hi = 0; }
      seg[b * 4 + 0] = src_end;
      seg[b * 4 + 1] = hyp_lo;
      seg[b * 4 + 2] = hyp_hi;
      seg[b * 4 + 3] = valid;
    }
  } else if (bx < 1540) {
    int i = (bx - 4) * 256 + threadIdx.x;
    int stride = 1536 * 256;
    const float4* xi = (const float4*)x;
    float4* oi = (float4*)out;
    for (; i < n4; i += stride) {
      float4 v = xi[i];
      oi[i] = v;  // default out = x (hyp rows overwritten by W2 epilogue)
      ushort4 r;
      r.x = f2bf(v.x); r.y = f2bf(v.y); r.z = f2bf(v.z); r.w = f2bf(v.w);
      *(ushort4*)(xbf + (size_t)i * 4) = r;
    }
  } else {
    float (*t)[65] = (float(*)[65])smem;
    int idx = bx - 1540;
    int z = idx / 144, rem = idx - z * 144;
    const float* W = (z == 0) ? W0 : (z == 1) ? W1 : (z == 2) ? W2
                    : (z == 3) ? W3 : (z == 4) ? W4 : W5;
    unsigned short* O = Wt + (size_t)z * DD * DD;
    int k0 = (rem / 12) * 64, n0 = (rem % 12) * 64;
    for (int i = threadIdx.x; i < 4096; i += 256) {
      int kk = i >> 6, nn = i & 63;
      t[kk][nn] = W[(size_t)(k0 + kk) * DD + n0 + nn];
    }
    __syncthreads();
    for (int i = threadIdx.x; i < 4096; i += 256) {
      int nn = i >> 6, kk = i & 63;
      O[(size_t)(n0 + nn) * DD + k0 + kk] = f2bf(t[kk][nn]);
    }
  }
}

// ---------------- LDS-staged GEMM core: 64x64 tile, BK=64, 4 waves of 32x32 ----------------
// which: 3=plain, 4=gelu (hyp rows, row-major bf16 out)
__device__ __forceinline__ void gemm_core(
    const unsigned short* __restrict__ A, const unsigned short* __restrict__ Wt,
    const float* __restrict__ bias, unsigned short* __restrict__ C,
    int b, int row0, int hi, int col0, int which, float rs,
    unsigned short (*Al)[64 * 64], unsigned short (*Bl)[64 * 64]) {
  int tid = threadIdx.x, w = tid >> 6, lane = tid & 63;
  int llo = lane & 15, lhi = lane >> 4;
  int wrg = w >> 1, wcg = w & 1;

  const unsigned short* Ab = A + (size_t)b * SS * DD;

  f32x4 acc[2][2];
#pragma unroll
  for (int i = 0; i < 2; ++i)
#pragma unroll
    for (int j = 0; j < 2; ++j) acc[i][j] = (f32x4){0.f, 0.f, 0.f, 0.f};

  auto STAGE = [&](int t, int buf) {
    int kk = t * 64;
#pragma unroll
    for (int j = 0; j < 2; ++j) {
      int s = j * 256 + tid;
      int row = s >> 3, c = s & 7;
      int gr = min(row0 + row, hi - 1);
      gl16(Ab + (size_t)gr * DD + kk + ((c ^ (row & 7)) * 8),
           &Al[buf][(size_t)(j * 256 + w * 64) * 8]);
    }
#pragma unroll
    for (int j = 0; j < 2; ++j) {
      int s = j * 256 + tid;
      int row = s >> 3, c = s & 7;
      gl16(Wt + (size_t)(col0 + row) * DD + kk + ((c ^ (row & 7)) * 8),
           &Bl[buf][(size_t)(j * 256 + w * 64) * 8]);
    }
  };

  STAGE(0, 0);
  __syncthreads();
  for (int t = 0; t < DD / 64; ++t) {
    int cur = t & 1;
    if (t + 1 < DD / 64) STAGE(t + 1, cur ^ 1);
#pragma unroll
    for (int ksub = 0; ksub < 2; ++ksub) {
      bf16x8 af[2], bfr[2];
#pragma unroll
      for (int mi = 0; mi < 2; ++mi) {
        int lr = wrg * 32 + mi * 16 + llo;
        int slot = lr * 8 + ((ksub * 4 + lhi) ^ (lr & 7));
        af[mi] = *(const bf16x8*)&Al[cur][(size_t)slot * 8];
      }
#pragma unroll
      for (int ni = 0; ni < 2; ++ni) {
        int lr = wcg * 32 + ni * 16 + llo;
        int slot = lr * 8 + ((ksub * 4 + lhi) ^ (lr & 7));
        bfr[ni] = *(const bf16x8*)&Bl[cur][(size_t)slot * 8];
      }
#pragma unroll
      for (int mi = 0; mi < 2; ++mi)
#pragma unroll
        for (int ni = 0; ni < 2; ++ni)
          acc[mi][ni] = MFMA16(af[mi], bfr[ni], acc[mi][ni]);
    }
    __syncthreads();
  }

#pragma unroll
  for (int mi = 0; mi < 2; ++mi)
#pragma unroll
    for (int ni = 0; ni < 2; ++ni) {
      int col = col0 + wcg * 32 + ni * 16 + llo;
      float bsv = bias[col];
      int rowb = row0 + wrg * 32 + mi * 16 + lhi * 4;
#pragma unroll
      for (int r = 0; r < 4; ++r) {
        int row = rowb + r;
        if (row < hi) {
          float v = (acc[mi][ni][r] + bsv) * rs;
          if (which == 4) v = gelu_tanh(v);
          C[((size_t)(b * SS + row)) * DD + col] = f2bf(v);
        }
      }
    }
}

// fused QKV: grid (24, 12, BB). x<12: Q over hyp; x>=12: paired K+V over src.
__global__ __launch_bounds__(256) void gemm_qkv(
    const unsigned short* __restrict__ A, const unsigned short* __restrict__ Wt3,
    const float* __restrict__ bq, const float* __restrict__ bk, const float* __restrict__ bv,
    unsigned short* __restrict__ Qo, unsigned short* __restrict__ Ko,
    unsigned short* __restrict__ Vto, const int* __restrict__ seg, float rs) {
  __shared__ unsigned short Al[2][64 * 64];
  __shared__ unsigned short B0l[2][64 * 64];
  __shared__ unsigned short B1l[2][64 * 64];
  const size_t WSZ = (size_t)DD * DD;
  int b = blockIdx.z;
  int col0 = (blockIdx.x % 12) * 64;
  int tid = threadIdx.x, w = tid >> 6, lane = tid & 63;
  int llo = lane & 15, lhi = lane >> 4;
  int wrg = w >> 1, wcg = w & 1;
  const unsigned short* Ab = A + (size_t)b * SS * DD;

  if (blockIdx.x < 12) {
    int lo = seg[b * 4 + 1], hi = seg[b * 4 + 2];
    int row0 = lo + (int)blockIdx.y * 64;
    if (row0 >= hi) return;
    gemm_core(A, Wt3, bq, Qo, b, row0, hi, col0, 3, rs, Al, B0l);
    return;
  }

  int hi = seg[b * 4 + 0];
  int row0 = 1 + (int)blockIdx.y * 64;
  if (row0 >= hi + 64) return;  // V zero-tail coverage
  const unsigned short* Wk_ = Wt3 + WSZ;
  const unsigned short* Wv_ = Wt3 + 2 * WSZ;

  f32x4 accK[2][2], accV[2][2];
#pragma unroll
  for (int i = 0; i < 2; ++i)
#pragma unroll
    for (int j = 0; j < 2; ++j) {
      accK[i][j] = (f32x4){0.f, 0.f, 0.f, 0.f};
      accV[i][j] = (f32x4){0.f, 0.f, 0.f, 0.f};
    }

  auto STAGE = [&](int t, int buf) {
    int kk = t * 64;
#pragma unroll
    for (int j = 0; j < 2; ++j) {
      int s = j * 256 + tid;
      int row = s >> 3, c = s & 7;
      int gr = min(row0 + row, hi - 1);
      gl16(Ab + (size_t)gr * DD + kk + ((c ^ (row & 7)) * 8),
           &Al[buf][(size_t)(j * 256 + w * 64) * 8]);
    }
#pragma unroll
    for (int j = 0; j < 2; ++j) {
      int s = j * 256 + tid;
      int row = s >> 3, c = s & 7;
      size_t woff = (size_t)(col0 + row) * DD + kk + ((c ^ (row & 7)) * 8);
      gl16(Wk_ + woff, &B0l[buf][(size_t)(j * 256 + w * 64) * 8]);
      gl16(Wv_ + woff, &B1l[buf][(size_t)(j * 256 + w * 64) * 8]);
    }
  };

  STAGE(0, 0);
  __syncthreads();
  for (int t = 0; t < DD / 64; ++t) {
    int cur = t & 1;
    if (t + 1 < DD / 64) STAGE(t + 1, cur ^ 1);
#pragma unroll
    for (int ksub = 0; ksub < 2; ++ksub) {
      bf16x8 af[2], bk2[2], bv2[2];
#pragma unroll
      for (int mi = 0; mi < 2; ++mi) {
        int lr = wrg * 32 + mi * 16 + llo;
        int slot = lr * 8 + ((ksub * 4 + lhi) ^ (lr & 7));
        af[mi] = *(const bf16x8*)&Al[cur][(size_t)slot * 8];
      }
#pragma unroll
      for (int ni = 0; ni < 2; ++ni) {
        int lr = wcg * 32 + ni * 16 + llo;
        int slot = lr * 8 + ((ksub * 4 + lhi) ^ (lr & 7));
        bk2[ni] = *(const bf16x8*)&B0l[cur][(size_t)slot * 8];
        bv2[ni] = *(const bf16x8*)&B1l[cur][(size_t)slot * 8];
      }
#pragma unroll
      for (int mi = 0; mi < 2; ++mi)
#pragma unroll
        for (int ni = 0; ni < 2; ++ni) {
          accK[mi][ni] = MFMA16(af[mi], bk2[ni], accK[mi][ni]);
          accV[mi][ni] = MFMA16(af[mi], bv2[ni], accV[mi][ni]);
        }
    }
    __syncthreads();
  }

#pragma unroll
  for (int mi = 0; mi < 2; ++mi)
#pragma unroll
    for (int ni = 0; ni < 2; ++ni) {
      int col = col0 + wcg * 32 + ni * 16 + llo;
      float bkv = bk[col], bvv = bv[col];
      int rowb = row0 + wrg * 32 + mi * 16 + lhi * 4;
#pragma unroll
      for (int r = 0; r < 4; ++r) {
        int row = rowb + r;
        if (row < hi)
          Ko[((size_t)(b * SS + row)) * DD + col] = f2bf(accK[mi][ni][r] + bkv);
        Vto[((size_t)b * DD + col) * SS + row] =
            (row < hi) ? f2bf(accV[mi][ni][r] + bvv) : (unsigned short)0;
      }
    }
}

// ---------------- split-K flash attention + fused last-block reduce ----------------
// grid (QT64, NCH_MAX, 32), block 256.
__global__ __launch_bounds__(256) void attn_split(
    const unsigned short* __restrict__ Q, const unsigned short* __restrict__ K,
    const unsigned short* __restrict__ Vt, char* __restrict__ part,
    unsigned short* __restrict__ ctx, int* __restrict__ cntAt,
    const int* __restrict__ seg) {
  int bh = blockIdx.z;
  int b = bh >> 3, h = bh & 7;
  int src_hi = seg[b * 4 + 0];
  int hyp_lo = seg[b * 4 + 1], hyp_hi = seg[b * 4 + 2];
  int q0b = hyp_lo + (int)blockIdx.x * 64;
  if (q0b >= hyp_hi) return;
  int ks = 1 + (int)blockIdx.y * CHUNK;
  if (ks >= src_hi) return;
  int ke = min(ks + CHUNK, src_hi);

  __shared__ unsigned short kls[64 * 128];
  __shared__ unsigned short vls[96 * 64];
  __shared__ unsigned short plds[4][1024];
  __shared__ int lastn;

  int tid = threadIdx.x;
  int w = tid >> 6, lane = tid & 63;
  int llo = lane & 15, lhi = lane >> 4;

  int qrow = min(q0b + w * 16 + llo, hyp_hi - 1);
  const unsigned short* qbase = Q + ((size_t)(b * SS + qrow)) * DD + h * DHD;
  bf16x8 qf[3];
#pragma unroll
  for (int df = 0; df < 3; ++df)
    qf[df] = *(const bf16x8*)(qbase + df * 32 + lhi * 8);

  const unsigned short* Kb = K + (size_t)b * SS * DD + h * DHD;
  const unsigned short* Vb = Vt + ((size_t)b * DD + h * DHD) * SS;

  f32x4 acc[6];
#pragma unroll
  for (int dt = 0; dt < 6; ++dt) acc[dt] = (f32x4){0.f, 0.f, 0.f, 0.f};
  float m_r[4] = {-1e30f, -1e30f, -1e30f, -1e30f};
  float l_r[4] = {0.f, 0.f, 0.f, 0.f};

  for (int k0 = ks; k0 < ke; k0 += 64) {
    __syncthreads();
#pragma unroll
    for (int j = 0; j < 4; ++j) {
      int s = j * 256 + tid;
      int row = s >> 4, sl = s & 15;
      int c = sl ^ (row & 7);
      int krow = min(k0 + row, ke - 1);
      gl16(Kb + (size_t)krow * DD + c * 8, &kls[(size_t)(j * 256 + w * 64) * 8]);
    }
#pragma unroll
    for (int j = 0; j < 3; ++j) {
      int s = j * 256 + tid;
      int row = s >> 3, sl = s & 7;
      int c = sl ^ (row & 7);
      gl16(Vb + (size_t)row * SS + k0 + c * 8, &vls[(size_t)(j * 256 + w * 64) * 8]);
    }
    __syncthreads();
    f32x4 s[4];
    __builtin_amdgcn_s_setprio(1);
#pragma unroll
    for (int t = 0; t < 4; ++t) {
      f32x4 st = (f32x4){0.f, 0.f, 0.f, 0.f};
      int row = t * 16 + llo;
#pragma unroll
      for (int df = 0; df < 3; ++df) {
        int slot = df * 4 + lhi;
        bf16x8 kf = *(const bf16x8*)&kls[row * 128 + ((slot ^ (row & 7)) << 3)];
        st = MFMA16(qf[df], kf, st);
      }
      s[t] = st;
    }
    __builtin_amdgcn_s_setprio(0);
    float mx[4] = {-1e30f, -1e30f, -1e30f, -1e30f};
#pragma unroll
    for (int t = 0; t < 4; ++t) {
      bool kv = (k0 + t * 16 + llo) < ke;
#pragma unroll
      for (int r = 0; r < 4; ++r) {
        float sv = kv ? s[t][r] : -1e30f;
        s[t][r] = sv;
        mx[r] = fmaxf(mx[r], sv);
      }
    }
#pragma unroll
    for (int st = 1; st < 16; st <<= 1)
#pragma unroll
      for (int r = 0; r < 4; ++r) mx[r] = fmaxf(mx[r], __shfl_xor(mx[r], st));

    float p[4][4];
#pragma unroll
    for (int r = 0; r < 4; ++r) {
      float mn = fmaxf(m_r[r], mx[r]);
      float sc = __expf(m_r[r] - mn);
      m_r[r] = mn;
      l_r[r] *= sc;
#pragma unroll
      for (int dt = 0; dt < 6; ++dt) acc[dt][r] *= sc;
      float ps = 0.f;
#pragma unroll
      for (int t = 0; t < 4; ++t) {
        float pv = (s[t][r] > -1e29f) ? __expf(s[t][r] - mn) : 0.f;
        p[t][r] = pv;
        ps += pv;
      }
#pragma unroll
      for (int st = 1; st < 16; st <<= 1) ps += __shfl_xor(ps, st);
      l_r[r] += ps;
    }
#pragma unroll
    for (int t = 0; t < 4; ++t)
#pragma unroll
      for (int r = 0; r < 4; ++r) {
        int qq = lhi * 4 + r, kk = t * 16 + llo;
        plds[w][qq * 64 + (kk ^ ((qq & 7) << 3))] = f2bf(p[t][r]);
      }
    bf16x8 pa[2];
#pragma unroll
    for (int kh = 0; kh < 2; ++kh) {
      int idx = llo * 64 + ((lhi * 8 + kh * 32) ^ ((llo & 7) << 3));
      pa[kh] = *(const bf16x8*)&plds[w][idx];
    }
    __builtin_amdgcn_s_setprio(1);
#pragma unroll
    for (int dt = 0; dt < 6; ++dt) {
      int row = dt * 16 + llo;
#pragma unroll
      for (int kh = 0; kh < 2; ++kh) {
        int slot = kh * 4 + lhi;
        bf16x8 vf = *(const bf16x8*)&vls[row * 64 + ((slot ^ (row & 7)) << 3)];
        acc[dt] = MFMA16(pa[kh], vf, acc[dt]);
      }
    }
    __builtin_amdgcn_s_setprio(0);
  }
  // write partial slot
  char* slot = part + (((size_t)bh * QT64 + blockIdx.x) * NCH_MAX + blockIdx.y) * SLOTB;
  unsigned short* pacc = (unsigned short*)slot;
  float* pml = (float*)(slot + 12288);
#pragma unroll
  for (int r = 0; r < 4; ++r) {
    int qq = w * 16 + lhi * 4 + r;
#pragma unroll
    for (int dt = 0; dt < 6; ++dt)
      pacc[qq * 96 + dt * 16 + llo] = f2bf(acc[dt][r]);
    if (llo == 0) { pml[qq] = m_r[r]; pml[64 + qq] = l_r[r]; }
  }
  // ---- fused reduce: last arriving chunk-block reduces this (bh, qtile) ----
  __threadfence();
  __syncthreads();
  if (tid == 0) {
    int nch = (src_hi - 1 + CHUNK - 1) / CHUNK;
    if (nch > NCH_MAX) nch = NCH_MAX;
    int old = atomicAdd(&cntAt[bh * QT64 + blockIdx.x], 1);
    lastn = (old == nch - 1) ? nch : 0;
  }
  __syncthreads();
  int nch = lastn;
  if (nch == 0) return;
  __threadfence();
  const char* base = part + ((size_t)bh * QT64 + blockIdx.x) * NCH_MAX * SLOTB;
  float* invL = (float*)kls;       // [64]
  float* scl = invL + 64;          // [NCH_MAX][64]
  if (tid < 64) {
    float mg = -1e30f;
    for (int c = 0; c < nch; ++c)
      mg = fmaxf(mg, ((const float*)(base + c * SLOTB + 12288))[tid]);
    float lg = 0.f;
    for (int c = 0; c < nch; ++c) {
      const float* p2 = (const float*)(base + c * SLOTB + 12288);
      float e = __expf(p2[tid] - mg);
      scl[c * 64 + tid] = e;
      lg += p2[64 + tid] * e;
    }
    invL[tid] = 1.f / lg;
  }
  __syncthreads();
  for (int i = tid; i < 64 * 96; i += 256) {
    int q = i / 96, d = i - q * 96;
    float v = 0.f;
    for (int c = 0; c < nch; ++c)
      v += bf2f(((const unsigned short*)(base + c * SLOTB))[i]) * scl[c * 64 + q];
    int qq = q0b + q;
    if (qq < hyp_hi)
      ctx[((size_t)(b * SS + qq)) * DD + h * DHD + d] = f2bf(v * invL[q]);
  }
}

// ---------------- Wo GEMM + fused LN1 epilogue ----------------
// grid (12, 11, BB)
__global__ __launch_bounds__(256) void gemm_wo_ln(
    const unsigned short* __restrict__ A, const unsigned short* __restrict__ Wt,
    const float* __restrict__ bias, unsigned short* __restrict__ Mha,
    const float* __restrict__ X, const float* __restrict__ g, const float* __restrict__ bta,
    float* __restrict__ X1f, unsigned short* __restrict__ X1bf,
    int* __restrict__ cntWo, const int* __restrict__ seg) {
  __shared__ unsigned short Al[2][64 * 64];
  __shared__ unsigned short Bl[2][64 * 64];
  __shared__ int lastA;
  int b = blockIdx.z;
  int lo = seg[b * 4 + 1], hi = seg[b * 4 + 2];
  int row0 = lo + (int)blockIdx.y * 64;
  if (row0 >= hi) return;
  gemm_core(A, Wt, bias, Mha, b, row0, hi, (int)blockIdx.x * 64, 3, 1.f, Al, Bl);

  int tid = threadIdx.x, w = tid >> 6, lane = tid & 63;
  __threadfence();
  __syncthreads();
  if (tid == 0) {
    int old = atomicAdd(&cntWo[b * 12 + blockIdx.y], 1);
    lastA = (old == 11) ? 1 : 0;
  }
  __syncthreads();
  if (!lastA) return;
  __threadfence();
  for (int rr = 0; rr < 16; ++rr) {
    int row = row0 + w * 16 + rr;
    if (row >= hi) break;
    size_t base = ((size_t)(b * SS + row)) * DD;
    float vx[12];
    float s = 0.f;
#pragma unroll
    for (int j = 0; j < 12; ++j) {
      int idx = lane + 64 * j;
      vx[j] = X[base + idx] + bf2f(Mha[base + idx]);
      s += vx[j];
    }
    float mean = wave_sum(s) * (1.f / DD);
    float vs = 0.f;
#pragma unroll
    for (int j = 0; j < 12; ++j) { float d = vx[j] - mean; vs += d * d; }
    float inv = rsqrtf(wave_sum(vs) * (1.f / DD) + 1e-5f);
#pragma unroll
    for (int j = 0; j < 12; ++j) {
      int idx = lane + 64 * j;
      float o = (vx[j] - mean) * inv * g[idx] + bta[idx];
      X1f[base + idx] = o;
      X1bf[base + idx] = f2bf(o);
    }
  }
}

// ---------------- W1 GEMM (gelu): grid (12, 11, BB) ----------------
__global__ __launch_bounds__(256) void gemm_mfma(
    const unsigned short* __restrict__ A, const unsigned short* __restrict__ Wt,
    const float* __restrict__ bias, unsigned short* __restrict__ C,
    const int* __restrict__ seg, int gelu) {
  __shared__ unsigned short Al[2][64 * 64];
  __shared__ unsigned short Bl[2][64 * 64];
  int b = blockIdx.z;
  int lo = seg[b * 4 + 1], hi = seg[b * 4 + 2];
  int row0 = lo + (int)blockIdx.y * 64;
  if (row0 >= hi) return;
  gemm_core(A, Wt, bias, C, b, row0, hi, (int)blockIdx.x * 64,
            gelu ? 4 : 3, 1.f, Al, Bl);
}

// ---------------- W2 GEMM + fused LN2+diff+scatter epilogue ----------------
// grid (12, 11, BB)
__global__ __launch_bounds__(256) void gemm_w2_ln(
    const unsigned short* __restrict__ A, const unsigned short* __restrict__ Wt,
    const float* __restrict__ bias, unsigned short* __restrict__ T2,
    const float* __restrict__ X, const float* __restrict__ X1f,
    const float* __restrict__ g2, const float* __restrict__ b2,
    const float* __restrict__ gd, const float* __restrict__ bd,
    float* __restrict__ Out, int* __restrict__ cntW2, const int* __restrict__ seg) {
  __shared__ unsigned short Al[2][64 * 64];
  __shared__ unsigned short Bl[2][64 * 64];
  __shared__ int lastA;
  int b = blockIdx.z;
  int lo = seg[b * 4 + 1], hi = seg[b * 4 + 2];
  int row0 = lo + (int)blockIdx.y * 64;
  if (row0 >= hi) return;
  gemm_core(A, Wt, bias, T2, b, row0, hi, (int)blockIdx.x * 64, 3, 1.f, Al, Bl);

  int tid = threadIdx.x, w = tid >> 6, lane = tid & 63;
  __threadfence();
  __syncthreads();
  if (tid == 0) {
    int old = atomicAdd(&cntW2[b * 12 + blockIdx.y], 1);
    lastA = (old == 11) ? 1 : 0;
  }
  __syncthreads();
  if (!lastA) return;
  __threadfence();
  for (int rr = 0; rr < 16; ++rr) {
    int row = row0 + w * 16 + rr;
    if (row >= hi) break;
    size_t base = ((size_t)(b * SS + row)) * DD;
    float y[12], xv[12];
    float s = 0.f;
#pragma unroll
    for (int j = 0; j < 12; ++j) {
      int idx = lane + 64 * j;
      y[j] = X1f[base + idx] + bf2f(T2[base + idx]);
      xv[j] = X[base + idx];
      s += y[j];
    }
    float mean = wave_sum(s) * (1.f / DD);
    float vs = 0.f;
#pragma unroll
    for (int j = 0; j < 12; ++j) { float d = y[j] - mean; vs += d * d; }
    float inv = rsqrtf(wave_sum(vs) * (1.f / DD) + 1e-5f);
    float z[12];
    float s2 = 0.f;
#pragma unroll
    for (int j = 0; j < 12; ++j) {
      int idx = lane + 64 * j;
      float x2 = (y[j] - mean) * inv * g2[idx] + b2[idx];
      z[j] = x2 - xv[j];
      s2 += z[j];
    }
    float mean2 = wave_sum(s2) * (1.f / DD);
    float vs2 = 0.f;
#pragma unroll
    for (int j = 0; j < 12; ++j) { float d = z[j] - mean2; vs2 += d * d; }
    float inv2 = rsqrtf(wave_sum(vs2) * (1.f / DD) + 1e-5f);
#pragma unroll
    for (int j = 0; j < 12; ++j) {
      int idx = lane + 64 * j;
      Out[base + idx] = xv[j] + (z[j] - mean2) * inv2 * gd[idx] + bd[idx];
    }
  }
}

extern "C" void kernel_launch(void* const* d_in, const int* in_sizes, int n_in,
                              void* d_out, int out_size, void* d_ws, size_t ws_size,
                              hipStream_t stream) {
  const float* x = (const float*)d_in[0];
  const int* ids = (const int*)d_in[1];
  const float* Wq = (const float*)d_in[3];
  const float* bq = (const float*)d_in[4];
  const float* Wk = (const float*)d_in[5];
  const float* bk = (const float*)d_in[6];
  const float* Wv = (const float*)d_in[7];
  const float* bv = (const float*)d_in[8];
  const float* Wo = (const float*)d_in[9];
  const float* bo = (const float*)d_in[10];
  const float* ln1g = (const float*)d_in[11];
  const float* ln1b = (const float*)d_in[12];
  const float* W1 = (const float*)d_in[13];
  const float* b1 = (const float*)d_in[14];
  const float* W2 = (const float*)d_in[15];
  const float* b2 = (const float*)d_in[16];
  const float* ln2g = (const float*)d_in[17];
  const float* ln2b = (const float*)d_in[18];
  const float* dng = (const float*)d_in[19];
  const float* dnb = (const float*)d_in[20];
  float* out = (float*)d_out;

  char* ws = (char*)d_ws;
  int* seg = (int*)ws;                    // 16 ints
  int* cnt = (int*)(ws + 64);             // 496 ints: cntAt[352], cntWo[48]@352, cntW2[48]@400
  int* cntAt = cnt;
  int* cntWo = cnt + 352;
  int* cntW2 = cnt + 400;
  size_t NBH = (size_t)BB * SS * DD * 2;  // 12.6 MB bf16
  char* Ap = ws + 2048;                   // x_bf -> ctx_bf -> h1_bf
  char* Bp = Ap + NBH;                    // q_bf -> mha_bf
  char* Cp = Bp + NBH;                    // k_bf -> t2_bf
  char* Dp = Cp + NBH;                    // vt_bf -> x1_bf
  char* Fp = Dp + NBH + 8192;             // attn partials (13.5 MB) -> x1f (25.2 MB)
  char* Gp = Fp + (size_t)BB * SS * DD * 4;  // wt: 6 x 768x768 bf16

  unsigned short* x_bf = (unsigned short*)Ap;
  unsigned short* ctx_bf = (unsigned short*)Ap;
  unsigned short* h1_bf = (unsigned short*)Ap;
  unsigned short* q_bf = (unsigned short*)Bp;
  unsigned short* mha_bf = (unsigned short*)Bp;
  unsigned short* k_bf = (unsigned short*)Cp;
  unsigned short* t2_bf = (unsigned short*)Cp;
  unsigned short* vt_bf = (unsigned short*)Dp;
  unsigned short* x1_bf = (unsigned short*)Dp;
  char* part = Fp;
  float* x1f = (float*)Fp;
  unsigned short* wt = (unsigned short*)Gp;
  const size_t WSZ = (size_t)DD * DD;

  const float rs = 0.1020620726159658f;  // 1/sqrt(96)

  prep<<<2404, 256, 0, stream>>>(ids, seg, cnt, x, x_bf, out, BB * SS * DD / 4,
                                 Wq, Wk, Wv, Wo, W1, W2, wt);

  gemm_qkv<<<dim3(24, 12, BB), 256, 0, stream>>>(
      x_bf, wt, bq, bk, bv, q_bf, k_bf, vt_bf, seg, rs);

  attn_split<<<dim3(QT64, NCH_MAX, 32), 256, 0, stream>>>(
      q_bf, k_bf, vt_bf, part, ctx_bf, cntAt, seg);

  gemm_wo_ln<<<dim3(12, 11, BB), 256, 0, stream>>>(
      ctx_bf, wt + 3 * WSZ, bo, mha_bf, x, ln1g, ln1b, x1f, x1_bf, cntWo, seg);

  gemm_mfma<<<dim3(12, 11, BB), 256, 0, stream>>>(x1_bf, wt + 4 * WSZ, b1, h1_bf, seg, 1);

  gemm_w2_ln<<<dim3(12, 11, BB), 256, 0, stream>>>(
      h1_bf, wt + 5 * WSZ, b2, t2_bf, x, x1f, ln2g, ln2b, dng, dnb, out, cntW2, seg);
}

// Round 15
// 149.944 us; speedup vs baseline: 2.9432x; 2.9432x over previous
//
#include <hip/hip_runtime.h>
#include <math.h>

#define BB 4
#define SS 2048
#define DD 768
#define HH 8
#define DHD 96
#define SEP_ID 102
#define CHUNK 352
#define NCH_MAX 3
#define QT64 11
#define SLOTB 12800  // 64q*96d bf16 (12288) + m[64],l[64] f32 (512)

typedef __attribute__((ext_vector_type(8))) short bf16x8;
typedef __attribute__((ext_vector_type(4))) float f32x4;

static __device__ __forceinline__ float gelu_tanh(float x) {
  float x3 = x * x * x;
  float t = tanhf(0.7978845608028654f * (x + 0.044715f * x3));
  return 0.5f * x * (1.0f + t);
}

static __device__ __forceinline__ unsigned short f2bf(float f) {
  unsigned int u = __float_as_uint(f);
  u = (u + 0x7FFF + ((u >> 16) & 1)) >> 16;
  return (unsigned short)u;
}

static __device__ __forceinline__ float bf2f(unsigned short u) {
  return __uint_as_float(((unsigned int)u) << 16);
}

#define MFMA16(A, B, C) __builtin_amdgcn_mfma_f32_16x16x32_bf16(A, B, C, 0, 0, 0)

// async global -> LDS, 16B per lane; LDS dest is wave-uniform base + lane*16
static __device__ __forceinline__ void gl16(const void* g, void* l) {
  __builtin_amdgcn_global_load_lds(
      (__attribute__((address_space(1))) unsigned int*)g,
      (__attribute__((address_space(3))) unsigned int*)l, 16, 0, 0);
}

// ---------------- fused prep: seg (4) + conv_bf (1536) + wtrans (864) ----------------
__global__ __launch_bounds__(256) void prep(
    const int* __restrict__ ids, int* __restrict__ seg,
    const float* __restrict__ x, unsigned short* __restrict__ xbf, int n4,
    const float* __restrict__ W0, const float* __restrict__ W1,
    const float* __restrict__ W2, const float* __restrict__ W3,
    const float* __restrict__ W4, const float* __restrict__ W5,
    unsigned short* __restrict__ Wt) {
  __shared__ char smem[64 * 65 * 4];
  int bx = blockIdx.x;
  if (bx < 4) {
    int* s1 = (int*)smem;
    int* s2 = s1 + 256;
    int b = bx;
    const int* row = ids + (size_t)b * SS;
    int m1 = SS, m2 = SS;
    for (int i = threadIdx.x; i < SS; i += 256) {
      if (row[i] == SEP_ID) {
        if (i < m1) { m2 = m1; m1 = i; }
        else if (i < m2) { m2 = i; }
      }
    }
    s1[threadIdx.x] = m1; s2[threadIdx.x] = m2;
    __syncthreads();
    for (int off = 128; off > 0; off >>= 1) {
      if (threadIdx.x < off) {
        int a1 = s1[threadIdx.x], a2 = s2[threadIdx.x];
        int b1 = s1[threadIdx.x + off], b2 = s2[threadIdx.x + off];
        s1[threadIdx.x] = min(a1, b1);
        s2[threadIdx.x] = min(max(a1, b1), min(a2, b2));
      }
      __syncthreads();
    }
    if (threadIdx.x == 0) {
      int first = s1[0], second = s2[0];
      bool has2 = (second < SS);
      int mid = SS / 2;
      int src_end = has2 ? first : mid;
      int hyp_lo = has2 ? (first + 1) : mid;
      int hyp_hi = has2 ? second : (SS - 1);
      int valid = ((src_end - 1) > 0 && (hyp_hi - hyp_lo) > 0) ? 1 : 0;
      if (!valid) { src_end = 1; hyp_lo = 0; hyp_hi = 0; }
      seg[b * 4 + 0] = src_end;
      seg[b * 4 + 1] = hyp_lo;
      seg[b * 4 + 2] = hyp_hi;
      seg[b * 4 + 3] = valid;
    }
  } else if (bx < 1540) {
    int i = (bx - 4) * 256 + threadIdx.x;
    int stride = 1536 * 256;
    const float4* xi = (const float4*)x;
    for (; i < n4; i += stride) {
      float4 v = xi[i];
      ushort4 r;
      r.x = f2bf(v.x); r.y = f2bf(v.y); r.z = f2bf(v.z); r.w = f2bf(v.w);
      *(ushort4*)(xbf + (size_t)i * 4) = r;
    }
  } else {
    float (*t)[65] = (float(*)[65])smem;
    int idx = bx - 1540;
    int z = idx / 144, rem = idx - z * 144;
    const float* W = (z == 0) ? W0 : (z == 1) ? W1 : (z == 2) ? W2
                    : (z == 3) ? W3 : (z == 4) ? W4 : W5;
    unsigned short* O = Wt + (size_t)z * DD * DD;
    int k0 = (rem / 12) * 64, n0 = (rem % 12) * 64;
    for (int i = threadIdx.x; i < 4096; i += 256) {
      int kk = i >> 6, nn = i & 63;
      t[kk][nn] = W[(size_t)(k0 + kk) * DD + n0 + nn];
    }
    __syncthreads();
    for (int i = threadIdx.x; i < 4096; i += 256) {
      int nn = i >> 6, kk = i & 63;
      O[(size_t)(n0 + nn) * DD + k0 + kk] = f2bf(t[kk][nn]);
    }
  }
}

// ---------------- LDS-staged GEMM core: 64x64 tile, BK=64, 4 waves of 32x32 ----------------
// source-pre-swizzled chunks (c ^ (row&7)) + swizzled reads.
// which: 3=plain, 4=gelu (hyp rows, row-major bf16 out)
__device__ __forceinline__ void gemm_core(
    const unsigned short* __restrict__ A, const unsigned short* __restrict__ Wt,
    const float* __restrict__ bias, unsigned short* __restrict__ C,
    int b, int row0, int hi, int col0, int which, float rs,
    unsigned short (*Al)[64 * 64], unsigned short (*Bl)[64 * 64]) {
  int tid = threadIdx.x, w = tid >> 6, lane = tid & 63;
  int llo = lane & 15, lhi = lane >> 4;
  int wrg = w >> 1, wcg = w & 1;

  const unsigned short* Ab = A + (size_t)b * SS * DD;

  f32x4 acc[2][2];
#pragma unroll
  for (int i = 0; i < 2; ++i)
#pragma unroll
    for (int j = 0; j < 2; ++j) acc[i][j] = (f32x4){0.f, 0.f, 0.f, 0.f};

  auto STAGE = [&](int t, int buf) {
    int kk = t * 64;
#pragma unroll
    for (int j = 0; j < 2; ++j) {
      int s = j * 256 + tid;
      int row = s >> 3, c = s & 7;
      int gr = min(row0 + row, hi - 1);
      gl16(Ab + (size_t)gr * DD + kk + ((c ^ (row & 7)) * 8),
           &Al[buf][(size_t)(j * 256 + w * 64) * 8]);
    }
#pragma unroll
    for (int j = 0; j < 2; ++j) {
      int s = j * 256 + tid;
      int row = s >> 3, c = s & 7;
      gl16(Wt + (size_t)(col0 + row) * DD + kk + ((c ^ (row & 7)) * 8),
           &Bl[buf][(size_t)(j * 256 + w * 64) * 8]);
    }
  };

  STAGE(0, 0);
  __syncthreads();
  for (int t = 0; t < DD / 64; ++t) {
    int cur = t & 1;
    if (t + 1 < DD / 64) STAGE(t + 1, cur ^ 1);
#pragma unroll
    for (int ksub = 0; ksub < 2; ++ksub) {
      bf16x8 af[2], bfr[2];
#pragma unroll
      for (int mi = 0; mi < 2; ++mi) {
        int lr = wrg * 32 + mi * 16 + llo;
        int slot = lr * 8 + ((ksub * 4 + lhi) ^ (lr & 7));
        af[mi] = *(const bf16x8*)&Al[cur][(size_t)slot * 8];
      }
#pragma unroll
      for (int ni = 0; ni < 2; ++ni) {
        int lr = wcg * 32 + ni * 16 + llo;
        int slot = lr * 8 + ((ksub * 4 + lhi) ^ (lr & 7));
        bfr[ni] = *(const bf16x8*)&Bl[cur][(size_t)slot * 8];
      }
#pragma unroll
      for (int mi = 0; mi < 2; ++mi)
#pragma unroll
        for (int ni = 0; ni < 2; ++ni)
          acc[mi][ni] = MFMA16(af[mi], bfr[ni], acc[mi][ni]);
    }
    __syncthreads();
  }

#pragma unroll
  for (int mi = 0; mi < 2; ++mi)
#pragma unroll
    for (int ni = 0; ni < 2; ++ni) {
      int col = col0 + wcg * 32 + ni * 16 + llo;
      float bsv = bias[col];
      int rowb = row0 + wrg * 32 + mi * 16 + lhi * 4;
#pragma unroll
      for (int r = 0; r < 4; ++r) {
        int row = rowb + r;
        if (row < hi) {
          float v = (acc[mi][ni][r] + bsv) * rs;
          if (which == 4) v = gelu_tanh(v);
          C[((size_t)(b * SS + row)) * DD + col] = f2bf(v);
        }
      }
    }
}

// fused QKV: grid (24, 12, BB).
// x<12: Q col-tile x over hyp rows. x>=12: paired K+V col-tile (x-12) over src rows,
// A staged once, 16 MFMA/K-tile, V stored transposed with zero tail.
__global__ __launch_bounds__(256) void gemm_qkv(
    const unsigned short* __restrict__ A, const unsigned short* __restrict__ Wt3,
    const float* __restrict__ bq, const float* __restrict__ bk, const float* __restrict__ bv,
    unsigned short* __restrict__ Qo, unsigned short* __restrict__ Ko,
    unsigned short* __restrict__ Vto, const int* __restrict__ seg, float rs) {
  __shared__ unsigned short Al[2][64 * 64];
  __shared__ unsigned short B0l[2][64 * 64];
  __shared__ unsigned short B1l[2][64 * 64];
  const size_t WSZ = (size_t)DD * DD;
  int b = blockIdx.z;
  int col0 = (blockIdx.x % 12) * 64;
  int tid = threadIdx.x, w = tid >> 6, lane = tid & 63;
  int llo = lane & 15, lhi = lane >> 4;
  int wrg = w >> 1, wcg = w & 1;
  const unsigned short* Ab = A + (size_t)b * SS * DD;

  if (blockIdx.x < 12) {
    // ---- Q over hyp rows ----
    int lo = seg[b * 4 + 1], hi = seg[b * 4 + 2];
    int row0 = lo + (int)blockIdx.y * 64;
    if (row0 >= hi) return;
    gemm_core(A, Wt3, bq, Qo, b, row0, hi, col0, 3, rs, Al, B0l);
    return;
  }

  // ---- paired K+V over src rows ----
  int hi = seg[b * 4 + 0];
  int row0 = 1 + (int)blockIdx.y * 64;
  if (row0 >= hi + 64) return;  // V needs zero tail [hi, hi+64)
  const unsigned short* Wk_ = Wt3 + WSZ;
  const unsigned short* Wv_ = Wt3 + 2 * WSZ;

  f32x4 accK[2][2], accV[2][2];
#pragma unroll
  for (int i = 0; i < 2; ++i)
#pragma unroll
    for (int j = 0; j < 2; ++j) {
      accK[i][j] = (f32x4){0.f, 0.f, 0.f, 0.f};
      accV[i][j] = (f32x4){0.f, 0.f, 0.f, 0.f};
    }

  auto STAGE = [&](int t, int buf) {
    int kk = t * 64;
#pragma unroll
    for (int j = 0; j < 2; ++j) {
      int s = j * 256 + tid;
      int row = s >> 3, c = s & 7;
      int gr = min(row0 + row, hi - 1);
      gl16(Ab + (size_t)gr * DD + kk + ((c ^ (row & 7)) * 8),
           &Al[buf][(size_t)(j * 256 + w * 64) * 8]);
    }
#pragma unroll
    for (int j = 0; j < 2; ++j) {
      int s = j * 256 + tid;
      int row = s >> 3, c = s & 7;
      size_t woff = (size_t)(col0 + row) * DD + kk + ((c ^ (row & 7)) * 8);
      gl16(Wk_ + woff, &B0l[buf][(size_t)(j * 256 + w * 64) * 8]);
      gl16(Wv_ + woff, &B1l[buf][(size_t)(j * 256 + w * 64) * 8]);
    }
  };

  STAGE(0, 0);
  __syncthreads();
  for (int t = 0; t < DD / 64; ++t) {
    int cur = t & 1;
    if (t + 1 < DD / 64) STAGE(t + 1, cur ^ 1);
#pragma unroll
    for (int ksub = 0; ksub < 2; ++ksub) {
      bf16x8 af[2], bk2[2], bv2[2];
#pragma unroll
      for (int mi = 0; mi < 2; ++mi) {
        int lr = wrg * 32 + mi * 16 + llo;
        int slot = lr * 8 + ((ksub * 4 + lhi) ^ (lr & 7));
        af[mi] = *(const bf16x8*)&Al[cur][(size_t)slot * 8];
      }
#pragma unroll
      for (int ni = 0; ni < 2; ++ni) {
        int lr = wcg * 32 + ni * 16 + llo;
        int slot = lr * 8 + ((ksub * 4 + lhi) ^ (lr & 7));
        bk2[ni] = *(const bf16x8*)&B0l[cur][(size_t)slot * 8];
        bv2[ni] = *(const bf16x8*)&B1l[cur][(size_t)slot * 8];
      }
#pragma unroll
      for (int mi = 0; mi < 2; ++mi)
#pragma unroll
        for (int ni = 0; ni < 2; ++ni) {
          accK[mi][ni] = MFMA16(af[mi], bk2[ni], accK[mi][ni]);
          accV[mi][ni] = MFMA16(af[mi], bv2[ni], accV[mi][ni]);
        }
    }
    __syncthreads();
  }

#pragma unroll
  for (int mi = 0; mi < 2; ++mi)
#pragma unroll
    for (int ni = 0; ni < 2; ++ni) {
      int col = col0 + wcg * 32 + ni * 16 + llo;
      float bkv = bk[col], bvv = bv[col];
      int rowb = row0 + wrg * 32 + mi * 16 + lhi * 4;
#pragma unroll
      for (int r = 0; r < 4; ++r) {
        int row = rowb + r;
        if (row < hi)
          Ko[((size_t)(b * SS + row)) * DD + col] = f2bf(accK[mi][ni][r] + bkv);
        // V transposed; zero tail rows [hi, row0+64) for PV tail reads
        Vto[((size_t)b * DD + col) * SS + row] =
            (row < hi) ? f2bf(accV[mi][ni][r] + bvv) : (unsigned short)0;
      }
    }
}

// hyp-rows GEMM: grid (12, 11, BB)
__global__ __launch_bounds__(256) void gemm_mfma(
    const unsigned short* __restrict__ A, const unsigned short* __restrict__ Wt,
    const float* __restrict__ bias, unsigned short* __restrict__ C,
    const int* __restrict__ seg, int gelu) {
  __shared__ unsigned short Al[2][64 * 64];
  __shared__ unsigned short Bl[2][64 * 64];
  int b = blockIdx.z;
  int lo = seg[b * 4 + 1], hi = seg[b * 4 + 2];
  int row0 = lo + (int)blockIdx.y * 64;
  if (row0 >= hi) return;
  gemm_core(A, Wt, bias, C, b, row0, hi, (int)blockIdx.x * 64,
            gelu ? 4 : 3, 1.f, Al, Bl);
}

// ---------------- split-K flash attention: 4 waves share gl16-staged K/V ----------------
// grid (QT64, NCH_MAX, 32), block 256. 64-query tile, chunk = 352 keys (nch=2 typical).
// kls rows: 16 x 16B slots (slots 12..15 = never-read filler from in-bounds addrs).
__global__ __launch_bounds__(256) void attn_split(
    const unsigned short* __restrict__ Q, const unsigned short* __restrict__ K,
    const unsigned short* __restrict__ Vt, char* __restrict__ part,
    const int* __restrict__ seg) {
  int bh = blockIdx.z;
  int b = bh >> 3, h = bh & 7;
  int src_hi = seg[b * 4 + 0];
  int hyp_lo = seg[b * 4 + 1], hyp_hi = seg[b * 4 + 2];
  int q0b = hyp_lo + (int)blockIdx.x * 64;
  if (q0b >= hyp_hi) return;
  int ks = 1 + (int)blockIdx.y * CHUNK;
  if (ks >= src_hi) return;
  int ke = min(ks + CHUNK, src_hi);

  __shared__ unsigned short kls[64 * 128];   // 64 keys x 16 slots (256B), XOR-swz
  __shared__ unsigned short vls[96 * 64];    // 96 d x 8 slots (128B), XOR-swz
  __shared__ unsigned short plds[4][1024];   // per-wave P

  int tid = threadIdx.x;
  int w = tid >> 6, lane = tid & 63;
  int llo = lane & 15, lhi = lane >> 4;

  int qrow = min(q0b + w * 16 + llo, hyp_hi - 1);
  const unsigned short* qbase = Q + ((size_t)(b * SS + qrow)) * DD + h * DHD;
  bf16x8 qf[3];
#pragma unroll
  for (int df = 0; df < 3; ++df)
    qf[df] = *(const bf16x8*)(qbase + df * 32 + lhi * 8);

  const unsigned short* Kb = K + (size_t)b * SS * DD + h * DHD;
  const unsigned short* Vb = Vt + ((size_t)b * DD + h * DHD) * SS;

  f32x4 acc[6];
#pragma unroll
  for (int dt = 0; dt < 6; ++dt) acc[dt] = (f32x4){0.f, 0.f, 0.f, 0.f};
  float m_r[4] = {-1e30f, -1e30f, -1e30f, -1e30f};
  float l_r[4] = {0.f, 0.f, 0.f, 0.f};

  for (int k0 = ks; k0 < ke; k0 += 64) {
    __syncthreads();
#pragma unroll
    for (int j = 0; j < 4; ++j) {
      int s = j * 256 + tid;
      int row = s >> 4, sl = s & 15;
      int c = sl ^ (row & 7);
      int krow = min(k0 + row, ke - 1);
      gl16(Kb + (size_t)krow * DD + c * 8,
           &kls[(size_t)(j * 256 + w * 64) * 8]);
    }
#pragma unroll
    for (int j = 0; j < 3; ++j) {
      int s = j * 256 + tid;
      int row = s >> 3, sl = s & 7;
      int c = sl ^ (row & 7);
      gl16(Vb + (size_t)row * SS + k0 + c * 8,
           &vls[(size_t)(j * 256 + w * 64) * 8]);
    }
    __syncthreads();
    f32x4 s[4];
    __builtin_amdgcn_s_setprio(1);
#pragma unroll
    for (int t = 0; t < 4; ++t) {
      f32x4 st = (f32x4){0.f, 0.f, 0.f, 0.f};
      int row = t * 16 + llo;
#pragma unroll
      for (int df = 0; df < 3; ++df) {
        int slot = df * 4 + lhi;
        bf16x8 kf = *(const bf16x8*)&kls[row * 128 + ((slot ^ (row & 7)) << 3)];
        st = MFMA16(qf[df], kf, st);
      }
      s[t] = st;
    }
    __builtin_amdgcn_s_setprio(0);
    float mx[4] = {-1e30f, -1e30f, -1e30f, -1e30f};
#pragma unroll
    for (int t = 0; t < 4; ++t) {
      bool kv = (k0 + t * 16 + llo) < ke;
#pragma unroll
      for (int r = 0; r < 4; ++r) {
        float sv = kv ? s[t][r] : -1e30f;
        s[t][r] = sv;
        mx[r] = fmaxf(mx[r], sv);
      }
    }
#pragma unroll
    for (int st = 1; st < 16; st <<= 1)
#pragma unroll
      for (int r = 0; r < 4; ++r) mx[r] = fmaxf(mx[r], __shfl_xor(mx[r], st));

    float p[4][4];
#pragma unroll
    for (int r = 0; r < 4; ++r) {
      float mn = fmaxf(m_r[r], mx[r]);
      float sc = __expf(m_r[r] - mn);
      m_r[r] = mn;
      l_r[r] *= sc;
#pragma unroll
      for (int dt = 0; dt < 6; ++dt) acc[dt][r] *= sc;
      float ps = 0.f;
#pragma unroll
      for (int t = 0; t < 4; ++t) {
        float pv = (s[t][r] > -1e29f) ? __expf(s[t][r] - mn) : 0.f;
        p[t][r] = pv;
        ps += pv;
      }
#pragma unroll
      for (int st = 1; st < 16; st <<= 1) ps += __shfl_xor(ps, st);
      l_r[r] += ps;
    }
#pragma unroll
    for (int t = 0; t < 4; ++t)
#pragma unroll
      for (int r = 0; r < 4; ++r) {
        int qq = lhi * 4 + r, kk = t * 16 + llo;
        plds[w][qq * 64 + (kk ^ ((qq & 7) << 3))] = f2bf(p[t][r]);
      }
    bf16x8 pa[2];
#pragma unroll
    for (int kh = 0; kh < 2; ++kh) {
      int idx = llo * 64 + ((lhi * 8 + kh * 32) ^ ((llo & 7) << 3));
      pa[kh] = *(const bf16x8*)&plds[w][idx];
    }
    __builtin_amdgcn_s_setprio(1);
#pragma unroll
    for (int dt = 0; dt < 6; ++dt) {
      int row = dt * 16 + llo;
#pragma unroll
      for (int kh = 0; kh < 2; ++kh) {
        int slot = kh * 4 + lhi;
        bf16x8 vf = *(const bf16x8*)&vls[row * 64 + ((slot ^ (row & 7)) << 3)];
        acc[dt] = MFMA16(pa[kh], vf, acc[dt]);
      }
    }
    __builtin_amdgcn_s_setprio(0);
  }
  char* slot = part + (((size_t)bh * QT64 + blockIdx.x) * NCH_MAX + blockIdx.y) * SLOTB;
  unsigned short* pacc = (unsigned short*)slot;
  float* pml = (float*)(slot + 12288);
#pragma unroll
  for (int r = 0; r < 4; ++r) {
    int qq = w * 16 + lhi * 4 + r;
#pragma unroll
    for (int dt = 0; dt < 6; ++dt)
      pacc[qq * 96 + dt * 16 + llo] = f2bf(acc[dt][r]);
    if (llo == 0) { pml[qq] = m_r[r]; pml[64 + qq] = l_r[r]; }
  }
}

// ---------------- split-K reduce -> ctx bf16 ----------------
__global__ __launch_bounds__(128) void attn_reduce(
    const char* __restrict__ part, unsigned short* __restrict__ ctx,
    const int* __restrict__ seg) {
  int bh = blockIdx.y;
  int b = bh >> 3, h = bh & 7;
  int src_hi = seg[b * 4 + 0];
  int hyp_lo = seg[b * 4 + 1], hyp_hi = seg[b * 4 + 2];
  int q0 = hyp_lo + (int)blockIdx.x * 16;
  if (q0 >= hyp_hi) return;
  int nch = (src_hi - 1 + CHUNK - 1) / CHUNK;
  if (nch > NCH_MAX) nch = NCH_MAX;
  int sub = blockIdx.x & 3;

  __shared__ float ml[NCH_MAX][32];
  __shared__ float Mg[16], invL[16], sc[NCH_MAX][16];
  int tid = threadIdx.x;
  const char* base = part + ((size_t)bh * QT64 + (blockIdx.x >> 2)) * NCH_MAX * SLOTB;
  for (int i = tid; i < 32 * nch; i += 128) {
    int c = i >> 5, j = i & 31;
    const float* pml = (const float*)(base + c * SLOTB + 12288);
    ml[c][j] = (j < 16) ? pml[sub * 16 + j] : pml[64 + sub * 16 + (j - 16)];
  }
  __syncthreads();
  if (tid < 16) {
    float mg = -1e30f;
    for (int c = 0; c < nch; ++c) mg = fmaxf(mg, ml[c][tid]);
    float lg = 0.f;
    for (int c = 0; c < nch; ++c) lg += ml[c][16 + tid] * __expf(ml[c][tid] - mg);
    Mg[tid] = mg;
    invL[tid] = 1.f / lg;
  }
  __syncthreads();
  for (int i = tid; i < 16 * nch; i += 128) {
    int c = i >> 4, q = i & 15;
    sc[c][q] = __expf(ml[c][q] - Mg[q]);
  }
  __syncthreads();
  for (int i = tid; i < 1536; i += 128) {
    int q = i / 96, d = i - q * 96;
    float v = 0.f;
    for (int c = 0; c < nch; ++c)
      v += bf2f(((const unsigned short*)(base + c * SLOTB))[(sub * 16 + q) * 96 + d]) * sc[c][q];
    int qq = q0 + q;
    if (qq < hyp_hi)
      ctx[((size_t)(b * SS + qq)) * DD + h * DHD + d] = f2bf(v * invL[q]);
  }
}

// ---------------- block reduction helper ----------------
__device__ __forceinline__ float block_sum(float v, float* sbuf) {
#pragma unroll
  for (int off = 32; off > 0; off >>= 1) v += __shfl_xor(v, off);
  int lane = threadIdx.x & 63, w = threadIdx.x >> 6;
  __syncthreads();
  if (lane == 0) sbuf[w] = v;
  __syncthreads();
  return sbuf[0] + sbuf[1] + sbuf[2] + sbuf[3];
}

// ---------------- x1 = LN(x + mha) over hyp rows; dual f32/bf16 out ----------------
__global__ __launch_bounds__(256) void ln_residual(
    const float* __restrict__ X, const unsigned short* __restrict__ Yin,
    const float* __restrict__ g, const float* __restrict__ bta,
    float* __restrict__ Out, unsigned short* __restrict__ OutBf,
    const int* __restrict__ seg) {
  int b = blockIdx.y;
  int row = seg[b * 4 + 1] + (int)blockIdx.x;
  if (row >= seg[b * 4 + 2]) return;
  __shared__ float sbuf[4];
  size_t base = ((size_t)(b * SS + row)) * DD;
  int tid = threadIdx.x;
  float v[3];
  float sum = 0.f;
#pragma unroll
  for (int r = 0; r < 3; ++r) {
    int i = tid + r * 256;
    v[r] = X[base + i] + bf2f(Yin[base + i]);
    sum += v[r];
  }
  float mean = block_sum(sum, sbuf) * (1.f / DD);
  float vs = 0.f;
#pragma unroll
  for (int r = 0; r < 3; ++r) { float d = v[r] - mean; vs += d * d; }
  float var = block_sum(vs, sbuf) * (1.f / DD);
  float inv = rsqrtf(var + 1e-5f);
#pragma unroll
  for (int r = 0; r < 3; ++r) {
    int i = tid + r * 256;
    float o = (v[r] - mean) * inv * g[i] + bta[i];
    Out[base + i] = o;
    OutBf[base + i] = f2bf(o);
  }
}

// ---------------- all rows: hyp -> x + LN(LN(x1+t2)-x); else -> x ----------------
__global__ __launch_bounds__(256) void ln2_diff_scatter(
    const float* __restrict__ X, const float* __restrict__ X1,
    const unsigned short* __restrict__ T2,
    const float* __restrict__ g2, const float* __restrict__ b2,
    const float* __restrict__ gd, const float* __restrict__ bd,
    float* __restrict__ Out, const int* __restrict__ seg) {
  int b = blockIdx.y, row = blockIdx.x;
  size_t base = ((size_t)(b * SS + row)) * DD;
  int tid = threadIdx.x;
  if (row < seg[b * 4 + 1] || row >= seg[b * 4 + 2]) {
#pragma unroll
    for (int r = 0; r < 3; ++r) {
      int i = tid + r * 256;
      Out[base + i] = X[base + i];
    }
    return;
  }
  __shared__ float sbuf[4];
  float y[3], xv[3];
  float sum = 0.f;
#pragma unroll
  for (int r = 0; r < 3; ++r) {
    int i = tid + r * 256;
    y[r] = X1[base + i] + bf2f(T2[base + i]);
    xv[r] = X[base + i];
    sum += y[r];
  }
  float mean = block_sum(sum, sbuf) * (1.f / DD);
  float vs = 0.f;
#pragma unroll
  for (int r = 0; r < 3; ++r) { float d = y[r] - mean; vs += d * d; }
  float var = block_sum(vs, sbuf) * (1.f / DD);
  float inv = rsqrtf(var + 1e-5f);
  float z[3];
  float sum2 = 0.f;
#pragma unroll
  for (int r = 0; r < 3; ++r) {
    int i = tid + r * 256;
    float x2 = (y[r] - mean) * inv * g2[i] + b2[i];
    z[r] = x2 - xv[r];
    sum2 += z[r];
  }
  float mean2 = block_sum(sum2, sbuf) * (1.f / DD);
  float vs2 = 0.f;
#pragma unroll
  for (int r = 0; r < 3; ++r) { float d = z[r] - mean2; vs2 += d * d; }
  float var2 = block_sum(vs2, sbuf) * (1.f / DD);
  float inv2 = rsqrtf(var2 + 1e-5f);
#pragma unroll
  for (int r = 0; r < 3; ++r) {
    int i = tid + r * 256;
    Out[base + i] = xv[r] + (z[r] - mean2) * inv2 * gd[i] + bd[i];
  }
}

extern "C" void kernel_launch(void* const* d_in, const int* in_sizes, int n_in,
                              void* d_out, int out_size, void* d_ws, size_t ws_size,
                              hipStream_t stream) {
  const float* x = (const float*)d_in[0];
  const int* ids = (const int*)d_in[1];
  const float* Wq = (const float*)d_in[3];
  const float* bq = (const float*)d_in[4];
  const float* Wk = (const float*)d_in[5];
  const float* bk = (const float*)d_in[6];
  const float* Wv = (const float*)d_in[7];
  const float* bv = (const float*)d_in[8];
  const float* Wo = (const float*)d_in[9];
  const float* bo = (const float*)d_in[10];
  const float* ln1g = (const float*)d_in[11];
  const float* ln1b = (const float*)d_in[12];
  const float* W1 = (const float*)d_in[13];
  const float* b1 = (const float*)d_in[14];
  const float* W2 = (const float*)d_in[15];
  const float* b2 = (const float*)d_in[16];
  const float* ln2g = (const float*)d_in[17];
  const float* ln2b = (const float*)d_in[18];
  const float* dng = (const float*)d_in[19];
  const float* dnb = (const float*)d_in[20];
  float* out = (float*)d_out;

  char* ws = (char*)d_ws;
  int* seg = (int*)ws;
  size_t NBH = (size_t)BB * SS * DD * 2;  // 12.6 MB bf16
  char* Ap = ws + 256;                    // x_bf -> ctx_bf -> h1_bf
  char* Bp = Ap + NBH;                    // q_bf -> mha_bf
  char* Cp = Bp + NBH;                    // k_bf -> t2_bf
  char* Dp = Cp + NBH;                    // vt_bf -> x1_bf
  char* Fp = Dp + NBH + 8192;             // attn partials (13.5 MB) -> x1f (25.2 MB)
  char* Gp = Fp + (size_t)BB * SS * DD * 4;  // wt: 6 x 768x768 bf16

  unsigned short* x_bf = (unsigned short*)Ap;
  unsigned short* ctx_bf = (unsigned short*)Ap;
  unsigned short* h1_bf = (unsigned short*)Ap;
  unsigned short* q_bf = (unsigned short*)Bp;
  unsigned short* mha_bf = (unsigned short*)Bp;
  unsigned short* k_bf = (unsigned short*)Cp;
  unsigned short* t2_bf = (unsigned short*)Cp;
  unsigned short* vt_bf = (unsigned short*)Dp;
  unsigned short* x1_bf = (unsigned short*)Dp;
  char* part = Fp;
  float* x1f = (float*)Fp;
  unsigned short* wt = (unsigned short*)Gp;
  const size_t WSZ = (size_t)DD * DD;

  const float rs = 0.1020620726159658f;  // 1/sqrt(96)

  prep<<<2404, 256, 0, stream>>>(ids, seg, x, x_bf, BB * SS * DD / 4,
                                 Wq, Wk, Wv, Wo, W1, W2, wt);

  gemm_qkv<<<dim3(24, 12, BB), 256, 0, stream>>>(
      x_bf, wt, bq, bk, bv, q_bf, k_bf, vt_bf, seg, rs);

  attn_split<<<dim3(QT64, NCH_MAX, 32), 256, 0, stream>>>(q_bf, k_bf, vt_bf, part, seg);
  attn_reduce<<<dim3(44, 32), 128, 0, stream>>>(part, ctx_bf, seg);

  gemm_mfma<<<dim3(12, 11, BB), 256, 0, stream>>>(ctx_bf, wt + 3 * WSZ, bo, mha_bf, seg, 0);
  ln_residual<<<dim3(704, BB), 256, 0, stream>>>(x, mha_bf, ln1g, ln1b, x1f, x1_bf, seg);
  gemm_mfma<<<dim3(12, 11, BB), 256, 0, stream>>>(x1_bf, wt + 4 * WSZ, b1, h1_bf, seg, 1);
  gemm_mfma<<<dim3(12, 11, BB), 256, 0, stream>>>(h1_bf, wt + 5 * WSZ, b2, t2_bf, seg, 0);
  ln2_diff_scatter<<<dim3(SS, BB), 256, 0, stream>>>(x, x1f, t2_bf, ln2g, ln2b, dng, dnb, out, seg);
}